// Round 2
// baseline (99.182 us; speedup 1.0000x reference)
//
#include <hip/hip_runtime.h>
#include <hip/hip_bf16.h>

// Quantum layer: 4 qubits, B=2^20 samples.
// state_out = V @ m  where V (16x16 complex) depends only on weights,
// m (16 real) = outer product of per-qubit (cos,sin) of x/2.
// out[w] = sum_j |state_out[j]|^2 * (1 - 2*bit_w(j)).
//
// R2 key change: V is wave-uniform -> read it from GLOBAL memory with
// compile-time-constant indices and no divergent control flow, so the
// compiler emits s_load (scalar pipe) and v_fmac_f32 with an SGPR operand.
// R1 kept V in LDS: 1024 broadcast ds_read_b32 per thread = ~79us LDS-issue
// bound. This version has ZERO LDS traffic in the hot kernel.

// ---------------- Kernel 1: build V from weights (16 threads) ----------------
__global__ void build_V_kernel(const float* __restrict__ w, float* __restrict__ V) {
    int k = threadIdx.x;
    if (k >= 16) return;

    float ar[16], ai[16];
#pragma unroll
    for (int j = 0; j < 16; ++j) { ar[j] = (j == k) ? 1.f : 0.f; ai[j] = 0.f; }

#pragma unroll
    for (int l = 0; l < 3; ++l) {
#pragma unroll
        for (int i = 0; i < 4; ++i) {
            float phi = w[l * 12 + i * 3 + 0];
            float th  = w[l * 12 + i * 3 + 1];
            float om  = w[l * 12 + i * 3 + 2];
            float ct = cosf(0.5f * th), st = sinf(0.5f * th);
            float alpha = 0.5f * (phi + om), beta = 0.5f * (phi - om);
            float sa, ca, sb, cb;
            sincosf(alpha, &sa, &ca);
            sincosf(beta,  &sb, &cb);
            float m00r =  ca * ct, m00i = -sa * ct;
            float m01r = -cb * st, m01i = -sb * st;
            float m10r =  cb * st, m10i = -sb * st;
            float m11r =  ca * ct, m11i =  sa * ct;
            int mask = 1 << i;
#pragma unroll
            for (int j = 0; j < 16; ++j) {
                if (j & mask) continue;
                int j1 = j | mask;
                float a0r = ar[j],  a0i = ai[j];
                float a1r = ar[j1], a1i = ai[j1];
                ar[j]  = m00r * a0r - m00i * a0i + m01r * a1r - m01i * a1i;
                ai[j]  = m00r * a0i + m00i * a0r + m01r * a1i + m01i * a1r;
                ar[j1] = m10r * a0r - m10i * a0i + m11r * a1r - m11i * a1i;
                ai[j1] = m10r * a0i + m10i * a0r + m11r * a1i + m11i * a1r;
            }
        }
        int r = (l % 3) + 1;
#pragma unroll
        for (int i = 0; i < 4; ++i) {
            int c = i, t = (i + r) & 3;
            int cm = 1 << c, tm = 1 << t;
#pragma unroll
            for (int j = 0; j < 16; ++j) {
                if ((j & cm) && !(j & tm)) {
                    int j2 = j | tm;
                    float tr = ar[j], ti = ai[j];
                    ar[j] = ar[j2]; ai[j] = ai[j2];
                    ar[j2] = tr;    ai[j2] = ti;
                }
            }
        }
    }

    // fold input phase (-i)^popcount(k) into column k
    int p = __popc(k) & 3;
    float pr = (p == 0) ? 1.f : (p == 2) ? -1.f : 0.f;
    float pi = (p == 1) ? -1.f : (p == 3) ? 1.f : 0.f;
#pragma unroll
    for (int j = 0; j < 16; ++j) {
        float vr = ar[j] * pr - ai[j] * pi;
        float vi = ar[j] * pi + ai[j] * pr;
        // layout per output row j: 16 re then 16 im, contiguous (32 floats)
        V[j * 32 + k]      = vr;
        V[j * 32 + 16 + k] = vi;
    }
}

// ---------------- Kernel 2: per-sample evaluation ----------------
#define SPT 4      // samples per thread
#define BLOCK 256

template <bool GUARD>
__launch_bounds__(BLOCK)
__global__ void qlayer_kernel(const float* __restrict__ x,
                              const float* __restrict__ V,
                              float* __restrict__ out, int B) {
    const int base = blockIdx.x * (BLOCK * SPT) + threadIdx.x;

    float m[SPT][16];
    float z[SPT][4];

#pragma unroll
    for (int s = 0; s < SPT; ++s) {
        int idx = base + s * BLOCK;
        float4 xv;
        if (!GUARD || idx < B) xv = ((const float4*)x)[idx];
        else xv = make_float4(0.f, 0.f, 0.f, 0.f);
        float c0, s0, c1, s1, c2, s2, c3, s3;
        __sincosf(0.5f * xv.x, &s0, &c0);
        __sincosf(0.5f * xv.y, &s1, &c1);
        __sincosf(0.5f * xv.z, &s2, &c2);
        __sincosf(0.5f * xv.w, &s3, &c3);

        float* ms = m[s];
        ms[0] = c0; ms[1] = s0;
        ms[2] = ms[0] * s1; ms[3] = ms[1] * s1;
        ms[0] *= c1;        ms[1] *= c1;
#pragma unroll
        for (int k = 0; k < 4; ++k) { ms[4 + k] = ms[k] * s2; ms[k] *= c2; }
#pragma unroll
        for (int k = 0; k < 8; ++k) { ms[8 + k] = ms[k] * s3; ms[k] *= c3; }

        z[s][0] = z[s][1] = z[s][2] = z[s][3] = 0.f;
    }

    // 16x16 complex x real matvec; V reads are uniform -> scalar loads.
#pragma unroll
    for (int j = 0; j < 16; ++j) {
        float re[SPT], im[SPT];
#pragma unroll
        for (int s = 0; s < SPT; ++s) { re[s] = 0.f; im[s] = 0.f; }
#pragma unroll
        for (int k = 0; k < 16; ++k) {
            const float vr = V[j * 32 + k];        // uniform -> SGPR
            const float vi = V[j * 32 + 16 + k];   // uniform -> SGPR
#pragma unroll
            for (int s = 0; s < SPT; ++s) {
                re[s] = fmaf(vr, m[s][k], re[s]);
                im[s] = fmaf(vi, m[s][k], im[s]);
            }
        }
#pragma unroll
        for (int s = 0; s < SPT; ++s) {
            float p = fmaf(re[s], re[s], im[s] * im[s]);
            z[s][0] += (j & 1) ? -p : p;
            z[s][1] += (j & 2) ? -p : p;
            z[s][2] += (j & 4) ? -p : p;
            z[s][3] += (j & 8) ? -p : p;
        }
    }

#pragma unroll
    for (int s = 0; s < SPT; ++s) {
        int idx = base + s * BLOCK;
        if (!GUARD || idx < B) {
            float4 o; o.x = z[s][0]; o.y = z[s][1]; o.z = z[s][2]; o.w = z[s][3];
            ((float4*)out)[idx] = o;
        }
    }
}

extern "C" void kernel_launch(void* const* d_in, const int* in_sizes, int n_in,
                              void* d_out, int out_size, void* d_ws, size_t ws_size,
                              hipStream_t stream) {
    const float* x = (const float*)d_in[0];
    const float* w = (const float*)d_in[1];
    float* out = (float*)d_out;
    float* V = (float*)d_ws;   // 512 floats of scratch

    int B = in_sizes[0] / 4;

    build_V_kernel<<<1, 64, 0, stream>>>(w, V);

    const int spb = BLOCK * SPT;
    if (B % spb == 0) {
        qlayer_kernel<false><<<B / spb, BLOCK, 0, stream>>>(x, V, out, B);
    } else {
        qlayer_kernel<true><<<(B + spb - 1) / spb, BLOCK, 0, stream>>>(x, V, out, B);
    }
}

// Round 3
// 92.169 us; speedup vs baseline: 1.0761x; 1.0761x over previous
//
#include <hip/hip_runtime.h>
#include <hip/hip_bf16.h>

// Quantum layer, 4 qubits, B=2^20.
// R3: full algebraic reduction. out_w(x) = m^T A_w m  (m = half-angle cos/sin
// outer product) is a multilinear polynomial in {1, cos x_q, sin x_q}^4:
//   out_w = sum_{t in {0,1,2}^4} C_w[t] * prod_q f_q(t_q),
//   f(0)=1, f(1)=cos x_q, f(2)=sin x_q.
// C (81 x float4) depends only on weights -> precomputed by build_C_kernel.
// Main kernel: 4 sincos + ~420 VALU/sample, 81 broadcast ds_read_b128/thread
// shared across 4 samples. (R1: 1024 ds_read_b32/thread = LDS-issue bound;
// R2: uniform global V reads, no better. Totals were harness-dominated.)

// ---------------- Kernel 1: build C[81] (float4) from weights ----------------
__global__ void build_C_kernel(const float* __restrict__ w, float4* __restrict__ C) {
    __shared__ float Vr[16][16];   // [j][k]
    __shared__ float Vi[16][16];
    __shared__ float A[4][16][16]; // [w][k][l]

    const int tid = threadIdx.x;

    // --- Phase 1: threads 0..15 build column k of the folded unitary V ---
    if (tid < 16) {
        const int k = tid;
        float ar[16], ai[16];
#pragma unroll
        for (int j = 0; j < 16; ++j) { ar[j] = (j == k) ? 1.f : 0.f; ai[j] = 0.f; }

#pragma unroll
        for (int l = 0; l < 3; ++l) {
#pragma unroll
            for (int i = 0; i < 4; ++i) {
                float phi = w[l * 12 + i * 3 + 0];
                float th  = w[l * 12 + i * 3 + 1];
                float om  = w[l * 12 + i * 3 + 2];
                float ct = cosf(0.5f * th), st = sinf(0.5f * th);
                float alpha = 0.5f * (phi + om), beta = 0.5f * (phi - om);
                float sa, ca, sb, cb;
                sincosf(alpha, &sa, &ca);
                sincosf(beta,  &sb, &cb);
                float m00r =  ca * ct, m00i = -sa * ct;
                float m01r = -cb * st, m01i = -sb * st;
                float m10r =  cb * st, m10i = -sb * st;
                float m11r =  ca * ct, m11i =  sa * ct;
                int mask = 1 << i;
#pragma unroll
                for (int j = 0; j < 16; ++j) {
                    if (j & mask) continue;
                    int j1 = j | mask;
                    float a0r = ar[j],  a0i = ai[j];
                    float a1r = ar[j1], a1i = ai[j1];
                    ar[j]  = m00r * a0r - m00i * a0i + m01r * a1r - m01i * a1i;
                    ai[j]  = m00r * a0i + m00i * a0r + m01r * a1i + m01i * a1r;
                    ar[j1] = m10r * a0r - m10i * a0i + m11r * a1r - m11i * a1i;
                    ai[j1] = m10r * a0i + m10i * a0r + m11r * a1i + m11i * a1r;
                }
            }
            int r = (l % 3) + 1;
#pragma unroll
            for (int i = 0; i < 4; ++i) {
                int c = i, t = (i + r) & 3;
                int cm = 1 << c, tm = 1 << t;
#pragma unroll
                for (int j = 0; j < 16; ++j) {
                    if ((j & cm) && !(j & tm)) {
                        int j2 = j | tm;
                        float tr = ar[j], ti = ai[j];
                        ar[j] = ar[j2]; ai[j] = ai[j2];
                        ar[j2] = tr;    ai[j2] = ti;
                    }
                }
            }
        }

        // fold the RX phase (-i)^popcount(k) of the input product state
        int p = __popc(k) & 3;
        float pr = (p == 0) ? 1.f : (p == 2) ? -1.f : 0.f;
        float pi = (p == 1) ? -1.f : (p == 3) ? 1.f : 0.f;
#pragma unroll
        for (int j = 0; j < 16; ++j) {
            Vr[j][k] = ar[j] * pr - ai[j] * pi;
            Vi[j][k] = ar[j] * pi + ai[j] * pr;
        }
    }
    __syncthreads();

    // --- Phase 2: A_w[k,l] = sum_j sigma_w(j) (Vr[j,k]Vr[j,l] + Vi[j,k]Vi[j,l]) ---
    {
        const int k = tid >> 4, l = tid & 15;
        float acc0 = 0.f, acc1 = 0.f, acc2 = 0.f, acc3 = 0.f;
#pragma unroll
        for (int j = 0; j < 16; ++j) {
            float p = Vr[j][k] * Vr[j][l] + Vi[j][k] * Vi[j][l];
            acc0 += (j & 1) ? -p : p;
            acc1 += (j & 2) ? -p : p;
            acc2 += (j & 4) ? -p : p;
            acc3 += (j & 8) ? -p : p;
        }
        A[0][k][l] = acc0; A[1][k][l] = acc1; A[2][k][l] = acc2; A[3][k][l] = acc3;
    }
    __syncthreads();

    // --- Phase 3: C_w[t] = (1/16) sum over 16 pair-choices of +-A_w[k,l] ---
    if (tid < 81) {
        int d[4];
        d[0] = tid % 3; d[1] = (tid / 3) % 3; d[2] = (tid / 9) % 3; d[3] = tid / 27;
        float acc0 = 0.f, acc1 = 0.f, acc2 = 0.f, acc3 = 0.f;
#pragma unroll
        for (int o = 0; o < 16; ++o) {
            int k = 0, l = 0; float sign = 1.f;
#pragma unroll
            for (int q = 0; q < 4; ++q) {
                int oq = (o >> q) & 1;
                if (d[q] == 2) { k |= oq << q; l |= (1 - oq) << q; }
                else {
                    k |= oq << q; l |= oq << q;
                    if (d[q] == 1 && oq == 1) sign = -sign;
                }
            }
            acc0 += sign * A[0][k][l];
            acc1 += sign * A[1][k][l];
            acc2 += sign * A[2][k][l];
            acc3 += sign * A[3][k][l];
        }
        const float inv16 = 0.0625f;
        C[tid] = make_float4(acc0 * inv16, acc1 * inv16, acc2 * inv16, acc3 * inv16);
    }
}

// ---------------- Kernel 2: per-sample polynomial evaluation ----------------
#define SPT 4
#define BLOCK 256

template <bool GUARD>
__launch_bounds__(BLOCK)
__global__ void qlayer_kernel(const float* __restrict__ x,
                              const float4* __restrict__ Cg,
                              float* __restrict__ out, int B) {
    __shared__ float4 C[81];
    if (threadIdx.x < 81) C[threadIdx.x] = Cg[threadIdx.x];
    __syncthreads();

    const int base = blockIdx.x * (BLOCK * SPT) + threadIdx.x;

    float c0[SPT], s0[SPT], c3[SPT], s3[SPT];
    float G9[SPT][9];        // products over wires 1,2: {1,c1,s1} x {1,c2,s2}
    float z[SPT][4];

#pragma unroll
    for (int s = 0; s < SPT; ++s) {
        int idx = base + s * BLOCK;
        float4 xv;
        if (!GUARD || idx < B) xv = ((const float4*)x)[idx];
        else xv = make_float4(0.f, 0.f, 0.f, 0.f);

        float c1, s1, c2, s2;
        __sincosf(xv.x, &s0[s], &c0[s]);   // wire 0 (full angle)
        __sincosf(xv.y, &s1, &c1);         // wire 1
        __sincosf(xv.z, &s2, &c2);         // wire 2
        __sincosf(xv.w, &s3[s], &c3[s]);   // wire 3

        G9[s][0] = 1.f;     G9[s][1] = c1;      G9[s][2] = s1;
        G9[s][3] = c2;      G9[s][4] = c1 * c2; G9[s][5] = s1 * c2;
        G9[s][6] = s2;      G9[s][7] = c1 * s2; G9[s][8] = s1 * s2;

        z[s][0] = z[s][1] = z[s][2] = z[s][3] = 0.f;
    }

    // t = t0 + 3*t1 + 9*t2 + 27*t3 ; combo = t1 + 3*t2 + 9*t3
#pragma unroll
    for (int t3 = 0; t3 < 3; ++t3) {
#pragma unroll
        for (int i9 = 0; i9 < 9; ++i9) {
            const int combo = i9 + 9 * t3;
            const float4 Ca = C[combo * 3 + 0];   // t0 = 0 (factor 1)
            const float4 Cb = C[combo * 3 + 1];   // t0 = 1 (factor cos x0)
            const float4 Cc = C[combo * 3 + 2];   // t0 = 2 (factor sin x0)
#pragma unroll
            for (int s = 0; s < SPT; ++s) {
                float g = G9[s][i9];
                if (t3 == 1) g *= c3[s];
                if (t3 == 2) g *= s3[s];
                float r0 = fmaf(c0[s], Cb.x, fmaf(s0[s], Cc.x, Ca.x));
                float r1 = fmaf(c0[s], Cb.y, fmaf(s0[s], Cc.y, Ca.y));
                float r2 = fmaf(c0[s], Cb.z, fmaf(s0[s], Cc.z, Ca.z));
                float r3 = fmaf(c0[s], Cb.w, fmaf(s0[s], Cc.w, Ca.w));
                z[s][0] = fmaf(g, r0, z[s][0]);
                z[s][1] = fmaf(g, r1, z[s][1]);
                z[s][2] = fmaf(g, r2, z[s][2]);
                z[s][3] = fmaf(g, r3, z[s][3]);
            }
        }
    }

#pragma unroll
    for (int s = 0; s < SPT; ++s) {
        int idx = base + s * BLOCK;
        if (!GUARD || idx < B) {
            float4 o; o.x = z[s][0]; o.y = z[s][1]; o.z = z[s][2]; o.w = z[s][3];
            ((float4*)out)[idx] = o;
        }
    }
}

extern "C" void kernel_launch(void* const* d_in, const int* in_sizes, int n_in,
                              void* d_out, int out_size, void* d_ws, size_t ws_size,
                              hipStream_t stream) {
    const float* x = (const float*)d_in[0];
    const float* w = (const float*)d_in[1];
    float* out = (float*)d_out;
    float4* C = (float4*)d_ws;   // 81 float4 of scratch

    int B = in_sizes[0] / 4;

    build_C_kernel<<<1, 256, 0, stream>>>(w, C);

    const int spb = BLOCK * SPT;
    if (B % spb == 0) {
        qlayer_kernel<false><<<B / spb, BLOCK, 0, stream>>>(x, C, out, B);
    } else {
        qlayer_kernel<true><<<(B + spb - 1) / spb, BLOCK, 0, stream>>>(x, C, out, B);
    }
}